// Round 2
// baseline (219.064 us; speedup 1.0000x reference)
//
#include <hip/hip_runtime.h>
#include <stdint.h>

#define S_LEN 4096
#define HDIM  768
#define NHEAD 12
#define DHEAD 64

typedef _Float16 f16;
typedef __attribute__((ext_vector_type(8)))  _Float16 f16x8;
typedef __attribute__((ext_vector_type(4)))  _Float16 f16x4;
typedef __attribute__((ext_vector_type(4)))  float    f32x4;
typedef __attribute__((ext_vector_type(16))) float    f32x16;

typedef __attribute__((address_space(1))) void gv_t;
typedef __attribute__((address_space(3))) void lv_t;

__device__ __forceinline__ void async_copy16(const void* g, void* l) {
  __builtin_amdgcn_global_load_lds((gv_t*)g, (lv_t*)l, 16, 0, 0);
}

__device__ __forceinline__ float fast_exp2(float x) {
#if __has_builtin(__builtin_amdgcn_exp2f)
  return __builtin_amdgcn_exp2f(x);
#else
  return exp2f(x);
#endif
}

__device__ __forceinline__ int swz4(int row) { return (row ^ (row >> 2)) & 3; }

// ---------------- workspace layout (heavy reuse) ----------------
constexpr size_t OFF_META = 0;                          // int kcount
constexpr size_t OFF_RIDX = 256;                        // int[4096] inverse map p->s
constexpr size_t OFF_XB   = 65536;                      // f16 x[4096*768]
constexpr size_t SZ_XB    = (size_t)S_LEN * HDIM * 2;
constexpr size_t OFF_WQKV = OFF_XB + SZ_XB;             // f16[3*768*768]; later PL
constexpr size_t SZ_WQKV  = (size_t)3 * HDIM * HDIM * 2;
constexpr size_t OFF_WO   = OFF_WQKV + SZ_WQKV;         // f16[768*768]
constexpr size_t SZ_WO    = (size_t)HDIM * HDIM * 2;
constexpr size_t OFF_Q    = OFF_WO + SZ_WO;             // f16[12][4096][64]
constexpr size_t SZ_HD    = (size_t)NHEAD * S_LEN * DHEAD * 2;
constexpr size_t OFF_K    = OFF_Q + SZ_HD;              // f16[12][4096][64] compacted
constexpr size_t OFF_VT   = OFF_K + SZ_HD;              // f16[12][64][4096] transposed+permuted V
constexpr size_t OFF_VR   = OFF_VT + SZ_HD;             // f16[12][4096][64] V rows; later PO split0
constexpr size_t OFF_PO1  = OFF_VR + SZ_HD;             // f16[12][4096][64] PO split1
constexpr size_t OFF_PO2  = OFF_PO1 + SZ_HD;            // PO split2
constexpr size_t OFF_PO3  = OFF_PO2 + SZ_HD;            // PO split3

// ---------------- prep: fp32->fp16 convert + mask compaction (inverse map) ----------------
__global__ __launch_bounds__(256) void k_prep(const float* __restrict__ x,
                                              const float* __restrict__ wq,
                                              const float* __restrict__ wk,
                                              const float* __restrict__ wv,
                                              const float* __restrict__ wo,
                                              const int* __restrict__ mi,
                                              f16* __restrict__ dst,
                                              int* __restrict__ ridx,
                                              int* __restrict__ meta) {
  __shared__ int s_flag;
  __shared__ int s_cnt[256];
  const int b = blockIdx.x, tid = threadIdx.x;
  if (b < 5376) {
    int i = b * 256 + tid;                   // 1376256 float4 units
    const float* src; int off;
    if (i < 786432) { src = x; off = i; }
    else {
      int j = i - 786432;
      int w = j / 147456;
      off = j - w * 147456;
      src = (w == 0) ? wq : (w == 1) ? wk : (w == 2) ? wv : wo;
    }
    float4 v = ((const float4*)src)[off];
    f16x4 h;
    h[0] = (f16)v.x; h[1] = (f16)v.y; h[2] = (f16)v.z; h[3] = (f16)v.w;
    ((f16x4*)dst)[i] = h;
    return;
  }
  // ---- mask block ----
  if (tid == 0) s_flag = 1;
  __syncthreads();
  int bad = 0;
  #pragma unroll
  for (int k = 0; k < 4; ++k) {
    int v = mi[k * 256 + tid];
    if (v != 0 && v != 1) bad = 1;
  }
  if (bad) atomicAnd(&s_flag, 0);
  __syncthreads();
  const int isInt = s_flag;
  const unsigned char* mu8 = (const unsigned char*)mi;
  int keep[16]; int cnt = 0;
  const int s0 = tid * 16;
  #pragma unroll
  for (int k = 0; k < 16; ++k) {
    int mval = isInt ? mi[s0 + k] : (int)mu8[s0 + k];
    keep[k] = (mval == 0) ? 1 : 0;           // True => masked out (excluded)
    cnt += keep[k];
    ridx[s0 + k] = 0;                        // zero-fill inverse map (pad-safe)
  }
  s_cnt[tid] = cnt;
  __syncthreads();
  for (int off = 1; off < 256; off <<= 1) {
    int t = (tid >= off) ? s_cnt[tid - off] : 0;
    __syncthreads();
    s_cnt[tid] += t;
    __syncthreads();
  }
  int base = s_cnt[tid] - cnt;               // exclusive prefix
  #pragma unroll
  for (int k = 0; k < 16; ++k) {
    if (keep[k]) { ridx[base] = s0 + k; ++base; }
  }
  if (tid == 255) meta[0] = s_cnt[255];
}

// ---------------- fused QKV projection GEMM, 2-phase double-buffered ---------------------
__global__ __launch_bounds__(256) void k_qkv(
    const f16* __restrict__ xb, const f16* __restrict__ wqkv,
    const float* __restrict__ bq, const float* __restrict__ bk, const float* __restrict__ bv,
    const int* __restrict__ ridx, const int* __restrict__ meta,
    f16* __restrict__ Qh, f16* __restrict__ Kc, f16* __restrict__ Vrow) {
  __shared__ __attribute__((aligned(16))) f16 lA[2][128 * 32];
  __shared__ __attribute__((aligned(16))) f16 lB[2][128 * 32];
  const int tid = threadIdx.x;
  const int wid = tid >> 6, lane = tid & 63;
  const int hf = lane >> 5, l31 = lane & 31;
  const int wm = wid >> 1, wn = wid & 1;
  const int tn = blockIdx.x;
  const int m0 = blockIdx.y * 128;
  const int mat = tn / 6;
  const int nb = (tn % 6) * 128;
  const int kc = meta[0];
  if (mat != 0 && m0 >= kc) return;          // fully-pad K/V tile
  const f16* wbase = wqkv + (size_t)mat * HDIM * HDIM;

  const int ar0 = tid >> 2, ar1 = 64 + (tid >> 2);
  const f16* asrc0;
  const f16* asrc1;
  if (mat == 0) {
    asrc0 = xb + (size_t)(m0 + ar0) * HDIM;
    asrc1 = xb + (size_t)(m0 + ar1) * HDIM;
  } else {
    int g0 = (m0 + ar0 < kc) ? ridx[m0 + ar0] : 0;
    int g1 = (m0 + ar1 < kc) ? ridx[m0 + ar1] : 0;
    asrc0 = xb + (size_t)g0 * HDIM;
    asrc1 = xb + (size_t)g1 * HDIM;
  }
  const int slot = tid & 3;
  const int gs0 = slot ^ swz4(ar0);
  const int gs1 = slot ^ swz4(ar1);

  auto stage = [&](int k0, int buf) {
    async_copy16((const char*)(asrc0 + k0) + gs0 * 16, (char*)&lA[buf][0] + (wid * 64) * 16);
    async_copy16((const char*)(asrc1 + k0) + gs1 * 16, (char*)&lA[buf][0] + (256 + wid * 64) * 16);
    async_copy16((const char*)(wbase + (size_t)(nb + ar0) * HDIM + k0) + gs0 * 16,
                 (char*)&lB[buf][0] + (wid * 64) * 16);
    async_copy16((const char*)(wbase + (size_t)(nb + ar1) * HDIM + k0) + gs1 * 16,
                 (char*)&lB[buf][0] + (256 + wid * 64) * 16);
  };

  f32x16 acc[2][2] = {};

  stage(0, 0);
  __syncthreads();
  int cur = 0;

  for (int k0 = 0; k0 < HDIM; k0 += 32) {
    const bool more = (k0 + 32 < HDIM);
    if (more) stage(k0 + 32, cur ^ 1);       // issue next K-step; hides under compute
    #pragma unroll
    for (int kk = 0; kk < 2; ++kk) {
      f16x8 af[2], bf[2];
      #pragma unroll
      for (int mi = 0; mi < 2; ++mi) {
        int row = wm * 64 + mi * 32 + l31;
        af[mi] = *(const f16x8*)&lA[cur][row * 32 + (((kk * 2 + hf) ^ swz4(row)) * 8)];
      }
      #pragma unroll
      for (int ni = 0; ni < 2; ++ni) {
        int row = wn * 64 + ni * 32 + l31;
        bf[ni] = *(const f16x8*)&lB[cur][row * 32 + (((kk * 2 + hf) ^ swz4(row)) * 8)];
      }
      #pragma unroll
      for (int mi = 0; mi < 2; ++mi)
        #pragma unroll
        for (int ni = 0; ni < 2; ++ni)
          acc[mi][ni] = __builtin_amdgcn_mfma_f32_32x32x16_f16(af[mi], bf[ni], acc[mi][ni], 0, 0, 0);
    }
    if (more) { __syncthreads(); cur ^= 1; }
  }

  const float* bias = (mat == 0) ? bq : (mat == 1) ? bk : bv;
  const float qscale = 0.125f * 1.44269504088896341f;  // 1/sqrt(64) * log2(e)
  f16* kvdst = (mat == 1) ? Kc : Vrow;
  #pragma unroll
  for (int mi = 0; mi < 2; ++mi) {
    #pragma unroll
    for (int ni = 0; ni < 2; ++ni) {
      int n = nb + wn * 64 + ni * 32 + l31;
      int head = n >> 6, d = n & 63;
      float b = bias[n];
      #pragma unroll
      for (int reg = 0; reg < 16; ++reg) {
        int s = m0 + wm * 64 + mi * 32 + (reg & 3) + 8 * (reg >> 2) + 4 * hf;
        float val = acc[mi][ni][reg] + b;
        if (mat == 0) {
          Qh[((size_t)head * S_LEN + s) * DHEAD + d] = (f16)(val * qscale);
        } else if (s < kc) {
          kvdst[((size_t)head * S_LEN + s) * DHEAD + d] = (f16)val;
        }
      }
    }
  }
}

// ---------------- V transpose [h][p][d] -> [h][d][rho] (key bits 2<->3 swapped) ----------
__global__ __launch_bounds__(256) void k_vt(const int* __restrict__ meta,
                                            const f16* __restrict__ Vrow,
                                            f16* __restrict__ Vtc,
                                            f16* __restrict__ Kc) {
  const int kc = meta[0];
  const int kcp = (kc + 63) & ~63;
  const int p0 = blockIdx.x * 64;
  const int h = blockIdx.y;
  const int tid = threadIdx.x;
  if (p0 >= kcp) return;
  if (p0 <= kc && kc < p0 + 64 && kc < kcp) {
    const int npad = kcp - kc;
    for (int u = tid; u < npad * 8; u += 256) {
      int r = kc + (u >> 3), c8 = u & 7;
      f16x8 z = {};
      *(f16x8*)&Kc[((size_t)h * S_LEN + r) * DHEAD + c8 * 8] = z;
    }
  }
  __shared__ __attribute__((aligned(16))) f16 lT[64 * 80];   // [d][p], stride 80
  for (int u = tid; u < 512; u += 256) {
    int d8 = u >> 6, p = u & 63;
    f16x8 v = {};
    if (p0 + p < kc) v = *(const f16x8*)&Vrow[((size_t)h * S_LEN + p0 + p) * DHEAD + d8 * 8];
    #pragma unroll
    for (int j = 0; j < 8; ++j) lT[(d8 * 8 + j) * 80 + p] = v[j];
  }
  __syncthreads();
  for (int w = tid; w < 512; w += 256) {
    int d = w >> 3, p8 = w & 7;
    int base16 = (p8 >> 1) * 16, half = p8 & 1;
    f16x4 lo = *(const f16x4*)&lT[d * 80 + base16 + half * 4];
    f16x4 hi = *(const f16x4*)&lT[d * 80 + base16 + 8 + half * 4];
    f16x8 o;
    o[0] = lo[0]; o[1] = lo[1]; o[2] = lo[2]; o[3] = lo[3];
    o[4] = hi[0]; o[5] = hi[1]; o[6] = hi[2]; o[7] = hi[3];
    *(f16x8*)&Vtc[((size_t)h * DHEAD + d) * S_LEN + p0 + p8 * 8] = o;
  }
}

// ---------------- flash attention: 64q/wave register-blocked, 4-way K-split --------------
// vs r1: each wave owns 64 queries (qf[2][4], accO[2][2]) so every af/vf LDS fragment
// feeds 2 MFMAs -> LDS-read per FLOP halved (was the co-critical pipe at ~10us/CU floor).
// Key-split widened 2->4 to keep 768 blocks (3/CU) despite 256 q/block.
__global__ __launch_bounds__(256, 3) void k_attn(
    const f16* __restrict__ Qh, const f16* __restrict__ Kc, const f16* __restrict__ Vtc,
    const int* __restrict__ meta,
    f16* __restrict__ PO0, f16* __restrict__ PO1,
    f16* __restrict__ PO2, f16* __restrict__ PO3,
    float* __restrict__ PL) {
  __shared__ __attribute__((aligned(16))) f16 lK[2][64 * 64];   // [buf][key][d] swizzled
  __shared__ __attribute__((aligned(16))) f16 lV[2][64 * 64];   // [buf][d][rho] swizzled
  const int tid = threadIdx.x;
  const int wid = tid >> 6, lane = tid & 63;
  const int hf = lane >> 5, l31 = lane & 31, r7 = l31 & 7;

  // XCD head-clustering: 768 blocks, 96 contiguous work units per XCD (<=2 heads of K/V).
  const int lid = blockIdx.x;
  const int w = ((lid & 7) * 96) + (lid >> 3);
  const int head = w >> 6;
  const int rem = w & 63;               // 4 splits x 16 q-blocks
  const int split = rem >> 4;
  const int qw = (rem & 15) * 256 + wid * 64;   // wave's 64-query base

  const int kc = meta[0];
  const int nkt = (kc + 63) >> 6;
  const int t0 = (split * nkt) >> 2;
  const int t1 = ((split + 1) * nkt) >> 2;

  // Q B-frags for both 32q halves: lane n = q = l31, k = dc*16 + hf*8 + j
  f16x8 qf[2][4];
  #pragma unroll
  for (int qb = 0; qb < 2; ++qb) {
    const f16* Qp = Qh + ((size_t)head * S_LEN + qw + qb * 32 + l31) * DHEAD;
    #pragma unroll
    for (int dc = 0; dc < 4; ++dc) qf[qb][dc] = *(const f16x8*)(Qp + dc * 16 + hf * 8);
  }

  f32x16 accO[2][2] = {};   // [qb][dh]
  float ls[2][2] = {};      // [qb][parity]

  const char* kbase = (const char*)(Kc + (size_t)head * S_LEN * DHEAD);
  const char* vbase = (const char*)(Vtc + (size_t)head * DHEAD * S_LEN);

  const int c0row = tid >> 3,         c0slot = tid & 7;
  const int c1row = (256 + tid) >> 3, c1slot = tid & 7;
  const int gs0 = c0slot ^ (c0row & 7);
  const int gs1 = c1slot ^ (c1row & 7);

  auto stage = [&](int t, int buf) {
    const int j0 = t * 64;
    async_copy16(kbase + (size_t)(j0 + c0row) * 128 + gs0 * 16,
                 (char*)&lK[buf][0] + (wid * 64) * 16);
    async_copy16(vbase + (size_t)c0row * (S_LEN * 2) + (size_t)j0 * 2 + gs0 * 16,
                 (char*)&lV[buf][0] + (wid * 64) * 16);
    async_copy16(kbase + (size_t)(j0 + c1row) * 128 + gs1 * 16,
                 (char*)&lK[buf][0] + (256 + wid * 64) * 16);
    async_copy16(vbase + (size_t)c1row * (S_LEN * 2) + (size_t)j0 * 2 + gs1 * 16,
                 (char*)&lV[buf][0] + (256 + wid * 64) * 16);
  };

  int cur = 0;
  if (t0 < t1) {
    stage(t0, 0);
    __syncthreads();
  }

  for (int t = t0; t < t1; ++t) {
    const bool more = (t + 1 < t1);
    if (more) stage(t + 1, cur ^ 1);

    #pragma unroll
    for (int mh = 0; mh < 2; ++mh) {
      // K A-frags: lane m = key = mh*32 + l31, k = dc*16 + hf*8 + j (shared by both qb)
      f16x8 af[4];
      const int arow = mh * 32 + l31;
      #pragma unroll
      for (int dc = 0; dc < 4; ++dc)
        af[dc] = *(const f16x8*)&lK[cur][arow * 64 + ((((dc << 1) | hf) ^ r7) * 8)];

      f16x8 pf[2][2];   // [qb][cc]
      #pragma unroll
      for (int qb = 0; qb < 2; ++qb) {
        f32x16 s = {};
        #pragma unroll
        for (int dc = 0; dc < 4; ++dc)
          s = __builtin_amdgcn_mfma_f32_32x32x16_f16(af[dc], qf[qb][dc], s, 0, 0, 0);
        #pragma unroll
        for (int u = 0; u < 16; ++u) {
          s[u] = fast_exp2(s[u]);
          ls[qb][u & 1] += s[u];
        }
        #pragma unroll
        for (int cc = 0; cc < 2; ++cc)
          #pragma unroll
          for (int u = 0; u < 8; ++u) pf[qb][cc][u] = (f16)s[8 * cc + u];
      }
      // PV: each vf fragment feeds both qb accumulators
      #pragma unroll
      for (int cc = 0; cc < 2; ++cc) {
        const int c2 = mh * 2 + cc;
        #pragma unroll
        for (int dh = 0; dh < 2; ++dh) {
          const int vrow = dh * 32 + l31;
          f16x8 vf = *(const f16x8*)&lV[cur][vrow * 64 + ((((c2 << 1) | hf) ^ r7) * 8)];
          accO[0][dh] = __builtin_amdgcn_mfma_f32_32x32x16_f16(pf[0][cc], vf, accO[0][dh], 0, 0, 0);
          accO[1][dh] = __builtin_amdgcn_mfma_f32_32x32x16_f16(pf[1][cc], vf, accO[1][dh], 0, 0, 0);
        }
      }
    }

    if (more) {
      __syncthreads();
      cur ^= 1;
    }
  }

  f16* PO = (split == 0) ? PO0 : (split == 1) ? PO1 : (split == 2) ? PO2 : PO3;
  #pragma unroll
  for (int qb = 0; qb < 2; ++qb) {
    float lsum = ls[qb][0] + ls[qb][1];
    lsum += __shfl_xor(lsum, 32);           // fold hf halves
    // pad keys are zero K rows -> P = 1 exactly; pad tile lives in the last split
    if (t1 == nkt) lsum -= (float)(nkt * 64 - kc);
    if (hf == 0)
      PL[((size_t)split * NHEAD + head) * S_LEN + qw + qb * 32 + l31] = lsum;
    #pragma unroll
    for (int dh = 0; dh < 2; ++dh)
      #pragma unroll
      for (int reg = 0; reg < 16; ++reg) {
        int row = (reg & 3) + 8 * (reg >> 2) + 4 * hf;
        PO[((size_t)head * S_LEN + qw + qb * 32 + row) * DHEAD + dh * 32 + l31] =
            (f16)accO[qb][dh][reg];
      }
  }
}

// ---------------- output projection GEMM, 2-phase dbuf + issue-early A-regs --------------
__global__ __launch_bounds__(256) void k_out(
    const f16* __restrict__ PO0, const f16* __restrict__ PO1,
    const f16* __restrict__ PO2, const f16* __restrict__ PO3,
    const float* __restrict__ PL, const f16* __restrict__ wo,
    const float* __restrict__ bo, float* __restrict__ out) {
  __shared__ __attribute__((aligned(16))) f16 lA[2][128 * 32];
  __shared__ __attribute__((aligned(16))) f16 lB[2][128 * 32];
  __shared__ float linv[NHEAD * 128];
  const int tid = threadIdx.x;
  const int wid = tid >> 6, lane = tid & 63;
  const int hf = lane >> 5, l31 = lane & 31;
  const int wm = wid >> 1, wn = wid & 1;
  const int nb = blockIdx.x * 128;
  const int m0 = blockIdx.y * 128;

  // per-block 1/l table: 12 heads x 128 rows, 4 splits combined
  for (int i = tid; i < NHEAD * 128; i += 256) {
    int h = i >> 7, r = i & 127;
    float l = PL[(size_t)h * S_LEN + m0 + r]
            + PL[(size_t)(NHEAD + h) * S_LEN + m0 + r]
            + PL[(size_t)(2 * NHEAD + h) * S_LEN + m0 + r]
            + PL[(size_t)(3 * NHEAD + h) * S_LEN + m0 + r];
    linv[i] = 1.0f / l;
  }
  __syncthreads();

  const int row0 = tid >> 2, row1 = 64 + (tid >> 2);
  const int slot = tid & 3;
  const int gsa0 = slot ^ swz4(row0);
  const int gsa1 = slot ^ swz4(row1);
  const float il0 = linv[0];  // placeholder to keep compiler happy (unused)

  f16x8 areg[2][4];
  // issue A-regs for step k0 (PO loads first so their vmcnt retires before B asyncs)
  auto loadA = [&](int k0) {
    const int head = k0 >> 6, d0 = k0 & 63;
    size_t pi0 = ((size_t)head * S_LEN + m0 + row0) * DHEAD + d0 + gsa0 * 8;
    size_t pi1 = ((size_t)head * S_LEN + m0 + row1) * DHEAD + d0 + gsa1 * 8;
    areg[0][0] = *(const f16x8*)(PO0 + pi0);
    areg[0][1] = *(const f16x8*)(PO1 + pi0);
    areg[0][2] = *(const f16x8*)(PO2 + pi0);
    areg[0][3] = *(const f16x8*)(PO3 + pi0);
    areg[1][0] = *(const f16x8*)(PO0 + pi1);
    areg[1][1] = *(const f16x8*)(PO1 + pi1);
    areg[1][2] = *(const f16x8*)(PO2 + pi1);
    areg[1][3] = *(const f16x8*)(PO3 + pi1);
  };
  // combine + scale + commit A-regs into LDS buf
  auto commitA = [&](int k0, int buf) {
    const int head = k0 >> 6;
    #pragma unroll
    for (int iss = 0; iss < 2; ++iss) {
      int row = iss ? row1 : row0;
      float il = linv[head * 128 + row];
      f16x8 av;
      #pragma unroll
      for (int u = 0; u < 8; ++u)
        av[u] = (f16)((((float)areg[iss][0][u] + (float)areg[iss][1][u]) +
                       ((float)areg[iss][2][u] + (float)areg[iss][3][u])) * il);
      *(f16x8*)&lA[buf][(iss * 256 + tid) * 8] = av;
    }
  };
  auto stageB = [&](int k0, int buf) {
    async_copy16((const char*)(wo + (size_t)(nb + row0) * HDIM + k0) + gsa0 * 16,
                 (char*)&lB[buf][0] + (wid * 64) * 16);
    async_copy16((const char*)(wo + (size_t)(nb + row1) * HDIM + k0) + gsa1 * 16,
                 (char*)&lB[buf][0] + (256 + wid * 64) * 16);
  };

  f32x16 acc[2][2] = {};

  loadA(0);
  stageB(0, 0);
  commitA(0, 0);
  __syncthreads();
  int cur = 0;

  for (int k0 = 0; k0 < HDIM; k0 += 32) {
    const bool more = (k0 + 32 < HDIM);
    if (more) { loadA(k0 + 32); stageB(k0 + 32, cur ^ 1); }
    #pragma unroll
    for (int kk = 0; kk < 2; ++kk) {
      f16x8 af[2], bf[2];
      #pragma unroll
      for (int mi = 0; mi < 2; ++mi) {
        int row = wm * 64 + mi * 32 + l31;
        af[mi] = *(const f16x8*)&lA[cur][row * 32 + (((kk * 2 + hf) ^ swz4(row)) * 8)];
      }
      #pragma unroll
      for (int ni = 0; ni < 2; ++ni) {
        int row = wn * 64 + ni * 32 + l31;
        bf[ni] = *(const f16x8*)&lB[cur][row * 32 + (((kk * 2 + hf) ^ swz4(row)) * 8)];
      }
      #pragma unroll
      for (int mi = 0; mi < 2; ++mi)
        #pragma unroll
        for (int ni = 0; ni < 2; ++ni)
          acc[mi][ni] = __builtin_amdgcn_mfma_f32_32x32x16_f16(af[mi], bf[ni], acc[mi][ni], 0, 0, 0);
    }
    if (more) {
      commitA(k0 + 32, cur ^ 1);   // A-load latency hid under compute; write after reads done
      __syncthreads();
      cur ^= 1;
    }
  }

  #pragma unroll
  for (int mi = 0; mi < 2; ++mi) {
    #pragma unroll
    for (int ni = 0; ni < 2; ++ni) {
      int n = nb + wn * 64 + ni * 32 + l31;
      float b = bo[n];
      #pragma unroll
      for (int reg = 0; reg < 16; ++reg) {
        int s = m0 + wm * 64 + mi * 32 + (reg & 3) + 8 * (reg >> 2) + 4 * hf;
        out[(size_t)s * HDIM + n] = acc[mi][ni][reg] + b;
      }
    }
  }
}

extern "C" void kernel_launch(void* const* d_in, const int* in_sizes, int n_in,
                              void* d_out, int out_size, void* d_ws, size_t ws_size,
                              hipStream_t stream) {
  const float* x  = (const float*)d_in[0];
  const float* Wq = (const float*)d_in[1];
  const float* bq = (const float*)d_in[2];
  const float* Wk = (const float*)d_in[3];
  const float* bk = (const float*)d_in[4];
  const float* Wv = (const float*)d_in[5];
  const float* bv = (const float*)d_in[6];
  const float* Wo = (const float*)d_in[7];
  const float* bo = (const float*)d_in[8];
  const int*   mask = (const int*)d_in[9];
  float* out = (float*)d_out;

  char* ws = (char*)d_ws;
  int* meta  = (int*)(ws + OFF_META);
  int* ridx  = (int*)(ws + OFF_RIDX);
  f16* xb    = (f16*)(ws + OFF_XB);
  f16* wqkv  = (f16*)(ws + OFF_WQKV);
  f16* wob   = (f16*)(ws + OFF_WO);
  f16* Qh    = (f16*)(ws + OFF_Q);
  f16* Kc    = (f16*)(ws + OFF_K);
  f16* Vtc   = (f16*)(ws + OFF_VT);
  f16* Vrow  = (f16*)(ws + OFF_VR);
  f16* PO0   = (f16*)(ws + OFF_VR);     // reuses Vrow after k_vt
  f16* PO1   = (f16*)(ws + OFF_PO1);
  f16* PO2   = (f16*)(ws + OFF_PO2);
  f16* PO3   = (f16*)(ws + OFF_PO3);
  float* PL  = (float*)(ws + OFF_WQKV); // reuses wqkv after k_qkv

  k_prep<<<dim3(5377), 256, 0, stream>>>(x, Wq, Wk, Wv, Wo, mask, xb, ridx, meta);
  k_qkv<<<dim3(18, 32), 256, 0, stream>>>(xb, wqkv, bq, bk, bv, ridx, meta, Qh, Kc, Vrow);
  k_vt<<<dim3(64, NHEAD), 256, 0, stream>>>(meta, Vrow, Vtc, Kc);
  k_attn<<<dim3(768), 256, 0, stream>>>(Qh, Kc, Vtc, meta, PO0, PO1, PO2, PO3, PL);
  k_out<<<dim3(6, 32), 256, 0, stream>>>(PO0, PO1, PO2, PO3, PL, wob, bo, out);
}

// Round 3
// 175.868 us; speedup vs baseline: 1.2456x; 1.2456x over previous
//
#include <hip/hip_runtime.h>
#include <stdint.h>

#define S_LEN 4096
#define HDIM  768
#define NHEAD 12
#define DHEAD 64

typedef _Float16 f16;
typedef __attribute__((ext_vector_type(8)))  _Float16 f16x8;
typedef __attribute__((ext_vector_type(4)))  _Float16 f16x4;
typedef __attribute__((ext_vector_type(4)))  float    f32x4;
typedef __attribute__((ext_vector_type(16))) float    f32x16;

typedef __attribute__((address_space(1))) void gv_t;
typedef __attribute__((address_space(3))) void lv_t;

__device__ __forceinline__ void async_copy16(const void* g, void* l) {
  __builtin_amdgcn_global_load_lds((gv_t*)g, (lv_t*)l, 16, 0, 0);
}

__device__ __forceinline__ float fast_exp2(float x) {
#if __has_builtin(__builtin_amdgcn_exp2f)
  return __builtin_amdgcn_exp2f(x);
#else
  return exp2f(x);
#endif
}

__device__ __forceinline__ int swz4(int row) { return (row ^ (row >> 2)) & 3; }

// ---------------- workspace layout (heavy reuse) ----------------
constexpr size_t OFF_META = 0;                          // int kcount
constexpr size_t OFF_RIDX = 256;                        // int[4096] inverse map p->s
constexpr size_t OFF_XB   = 65536;                      // f16 x[4096*768]
constexpr size_t SZ_XB    = (size_t)S_LEN * HDIM * 2;
constexpr size_t OFF_WQKV = OFF_XB + SZ_XB;             // f16[3*768*768]; later PL
constexpr size_t SZ_WQKV  = (size_t)3 * HDIM * HDIM * 2;
constexpr size_t OFF_WO   = OFF_WQKV + SZ_WQKV;         // f16[768*768]
constexpr size_t SZ_WO    = (size_t)HDIM * HDIM * 2;
constexpr size_t OFF_Q    = OFF_WO + SZ_WO;             // f16[12][4096][64]
constexpr size_t SZ_HD    = (size_t)NHEAD * S_LEN * DHEAD * 2;
constexpr size_t OFF_K    = OFF_Q + SZ_HD;              // f16[12][4096][64] compacted
constexpr size_t OFF_VT   = OFF_K + SZ_HD;              // f16[12][64][4096] transposed+permuted V
constexpr size_t OFF_VR   = OFF_VT + SZ_HD;             // f16[12][4096][64] V rows; later PO split0
constexpr size_t OFF_PO1  = OFF_VR + SZ_HD;             // f16[12][4096][64] PO split1

// ---------------- prep: fp32->fp16 convert + mask compaction (inverse map) ----------------
__global__ __launch_bounds__(256) void k_prep(const float* __restrict__ x,
                                              const float* __restrict__ wq,
                                              const float* __restrict__ wk,
                                              const float* __restrict__ wv,
                                              const float* __restrict__ wo,
                                              const int* __restrict__ mi,
                                              f16* __restrict__ dst,
                                              int* __restrict__ ridx,
                                              int* __restrict__ meta) {
  __shared__ int s_flag;
  __shared__ int s_cnt[256];
  const int b = blockIdx.x, tid = threadIdx.x;
  if (b < 5376) {
    int i = b * 256 + tid;                   // 1376256 float4 units
    const float* src; int off;
    if (i < 786432) { src = x; off = i; }
    else {
      int j = i - 786432;
      int w = j / 147456;
      off = j - w * 147456;
      src = (w == 0) ? wq : (w == 1) ? wk : (w == 2) ? wv : wo;
    }
    float4 v = ((const float4*)src)[off];
    f16x4 h;
    h[0] = (f16)v.x; h[1] = (f16)v.y; h[2] = (f16)v.z; h[3] = (f16)v.w;
    ((f16x4*)dst)[i] = h;
    return;
  }
  // ---- mask block ----
  if (tid == 0) s_flag = 1;
  __syncthreads();
  int bad = 0;
  #pragma unroll
  for (int k = 0; k < 4; ++k) {
    int v = mi[k * 256 + tid];
    if (v != 0 && v != 1) bad = 1;
  }
  if (bad) atomicAnd(&s_flag, 0);
  __syncthreads();
  const int isInt = s_flag;
  const unsigned char* mu8 = (const unsigned char*)mi;
  int keep[16]; int cnt = 0;
  const int s0 = tid * 16;
  #pragma unroll
  for (int k = 0; k < 16; ++k) {
    int mval = isInt ? mi[s0 + k] : (int)mu8[s0 + k];
    keep[k] = (mval == 0) ? 1 : 0;           // True => masked out (excluded)
    cnt += keep[k];
    ridx[s0 + k] = 0;                        // zero-fill inverse map (pad-safe)
  }
  s_cnt[tid] = cnt;
  __syncthreads();
  for (int off = 1; off < 256; off <<= 1) {
    int t = (tid >= off) ? s_cnt[tid - off] : 0;
    __syncthreads();
    s_cnt[tid] += t;
    __syncthreads();
  }
  int base = s_cnt[tid] - cnt;               // exclusive prefix
  #pragma unroll
  for (int k = 0; k < 16; ++k) {
    if (keep[k]) { ridx[base] = s0 + k; ++base; }
  }
  if (tid == 255) meta[0] = s_cnt[255];
}

// ---------------- fused QKV projection GEMM (32x32x16 MFMA, compacted K/V rows) ---------
__global__ __launch_bounds__(256) void k_qkv(
    const f16* __restrict__ xb, const f16* __restrict__ wqkv,
    const float* __restrict__ bq, const float* __restrict__ bk, const float* __restrict__ bv,
    const int* __restrict__ ridx, const int* __restrict__ meta,
    f16* __restrict__ Qh, f16* __restrict__ Kc, f16* __restrict__ Vrow) {
  __shared__ __attribute__((aligned(16))) f16 lA[128 * 32];
  __shared__ __attribute__((aligned(16))) f16 lB[128 * 32];
  const int tid = threadIdx.x;
  const int wid = tid >> 6, lane = tid & 63;
  const int hf = lane >> 5, l31 = lane & 31;
  const int wm = wid >> 1, wn = wid & 1;
  const int tn = blockIdx.x;
  const int m0 = blockIdx.y * 128;
  const int mat = tn / 6;
  const int nb = (tn % 6) * 128;
  const int kc = meta[0];
  if (mat != 0 && m0 >= kc) return;          // fully-pad K/V tile
  const f16* wbase = wqkv + (size_t)mat * HDIM * HDIM;

  const int ar0 = tid >> 2, ar1 = 64 + (tid >> 2);
  const f16* asrc0;
  const f16* asrc1;
  if (mat == 0) {
    asrc0 = xb + (size_t)(m0 + ar0) * HDIM;
    asrc1 = xb + (size_t)(m0 + ar1) * HDIM;
  } else {
    int g0 = (m0 + ar0 < kc) ? ridx[m0 + ar0] : 0;
    int g1 = (m0 + ar1 < kc) ? ridx[m0 + ar1] : 0;
    asrc0 = xb + (size_t)g0 * HDIM;
    asrc1 = xb + (size_t)g1 * HDIM;
  }
  const int slot = tid & 3;
  const int gs0 = slot ^ swz4(ar0);
  const int gs1 = slot ^ swz4(ar1);

  f32x16 acc[2][2] = {};

  for (int k0 = 0; k0 < HDIM; k0 += 32) {
    async_copy16((const char*)(asrc0 + k0) + gs0 * 16, (char*)lA + (wid * 64) * 16);
    async_copy16((const char*)(asrc1 + k0) + gs1 * 16, (char*)lA + (256 + wid * 64) * 16);
    async_copy16((const char*)(wbase + (size_t)(nb + ar0) * HDIM + k0) + gs0 * 16,
                 (char*)lB + (wid * 64) * 16);
    async_copy16((const char*)(wbase + (size_t)(nb + ar1) * HDIM + k0) + gs1 * 16,
                 (char*)lB + (256 + wid * 64) * 16);
    __syncthreads();
    #pragma unroll
    for (int kk = 0; kk < 2; ++kk) {
      f16x8 af[2], bf[2];
      #pragma unroll
      for (int mi = 0; mi < 2; ++mi) {
        int row = wm * 64 + mi * 32 + l31;
        af[mi] = *(const f16x8*)&lA[row * 32 + (((kk * 2 + hf) ^ swz4(row)) * 8)];
      }
      #pragma unroll
      for (int ni = 0; ni < 2; ++ni) {
        int row = wn * 64 + ni * 32 + l31;
        bf[ni] = *(const f16x8*)&lB[row * 32 + (((kk * 2 + hf) ^ swz4(row)) * 8)];
      }
      #pragma unroll
      for (int mi = 0; mi < 2; ++mi)
        #pragma unroll
        for (int ni = 0; ni < 2; ++ni)
          acc[mi][ni] = __builtin_amdgcn_mfma_f32_32x32x16_f16(af[mi], bf[ni], acc[mi][ni], 0, 0, 0);
    }
    __syncthreads();
  }

  const float* bias = (mat == 0) ? bq : (mat == 1) ? bk : bv;
  const float qscale = 0.125f * 1.44269504088896341f;  // 1/sqrt(64) * log2(e)
  f16* kvdst = (mat == 1) ? Kc : Vrow;
  #pragma unroll
  for (int mi = 0; mi < 2; ++mi) {
    #pragma unroll
    for (int ni = 0; ni < 2; ++ni) {
      int n = nb + wn * 64 + ni * 32 + l31;
      int head = n >> 6, d = n & 63;
      float b = bias[n];
      #pragma unroll
      for (int reg = 0; reg < 16; ++reg) {
        int s = m0 + wm * 64 + mi * 32 + (reg & 3) + 8 * (reg >> 2) + 4 * hf;
        float val = acc[mi][ni][reg] + b;
        if (mat == 0) {
          Qh[((size_t)head * S_LEN + s) * DHEAD + d] = (f16)(val * qscale);
        } else if (s < kc) {
          kvdst[((size_t)head * S_LEN + s) * DHEAD + d] = (f16)val;
        }
      }
    }
  }
}

// ---------------- V transpose [h][p][d] -> [h][d][rho] (key bits 2<->3 swapped) ----------
__global__ __launch_bounds__(256) void k_vt(const int* __restrict__ meta,
                                            const f16* __restrict__ Vrow,
                                            f16* __restrict__ Vtc,
                                            f16* __restrict__ Kc) {
  const int kc = meta[0];
  const int kcp = (kc + 63) & ~63;
  const int p0 = blockIdx.x * 64;
  const int h = blockIdx.y;
  const int tid = threadIdx.x;
  if (p0 >= kcp) return;
  if (p0 <= kc && kc < p0 + 64 && kc < kcp) {
    const int npad = kcp - kc;
    for (int u = tid; u < npad * 8; u += 256) {
      int r = kc + (u >> 3), c8 = u & 7;
      f16x8 z = {};
      *(f16x8*)&Kc[((size_t)h * S_LEN + r) * DHEAD + c8 * 8] = z;
    }
  }
  __shared__ __attribute__((aligned(16))) f16 lT[64 * 80];   // [d][p], stride 80
  for (int u = tid; u < 512; u += 256) {
    int d8 = u >> 6, p = u & 63;
    f16x8 v = {};
    if (p0 + p < kc) v = *(const f16x8*)&Vrow[((size_t)h * S_LEN + p0 + p) * DHEAD + d8 * 8];
    #pragma unroll
    for (int j = 0; j < 8; ++j) lT[(d8 * 8 + j) * 80 + p] = v[j];
  }
  __syncthreads();
  for (int w = tid; w < 512; w += 256) {
    int d = w >> 3, p8 = w & 7;
    int base16 = (p8 >> 1) * 16, half = p8 & 1;
    f16x4 lo = *(const f16x4*)&lT[d * 80 + base16 + half * 4];
    f16x4 hi = *(const f16x4*)&lT[d * 80 + base16 + 8 + half * 4];
    f16x8 o;
    o[0] = lo[0]; o[1] = lo[1]; o[2] = lo[2]; o[3] = lo[3];
    o[4] = hi[0]; o[5] = hi[1]; o[6] = hi[2]; o[7] = hi[3];
    *(f16x8*)&Vtc[((size_t)h * DHEAD + d) * S_LEN + p0 + p8 * 8] = o;
  }
}

// ---------------- flash attention: r1 structure + coalesced PO store via LDS bounce ------
__global__ __launch_bounds__(256, 3) void k_attn(
    const f16* __restrict__ Qh, const f16* __restrict__ Kc, const f16* __restrict__ Vtc,
    const int* __restrict__ meta, f16* __restrict__ PO0, f16* __restrict__ PO1,
    float* __restrict__ PL) {
  __shared__ __attribute__((aligned(16))) f16 lK[2][64 * 64];   // [buf][key][d] swizzled
  __shared__ __attribute__((aligned(16))) f16 lV[2][64 * 64];   // [buf][d][rho] swizzled
  const int tid = threadIdx.x;
  const int wid = tid >> 6, lane = tid & 63;
  const int hf = lane >> 5, l31 = lane & 31, r7 = l31 & 7;

  // XCD head-clustering: 768 blocks, 96 contiguous work units per XCD (<=2 heads of K/V).
  const int lid = blockIdx.x;
  const int w = ((lid & 7) * 96) + (lid >> 3);
  const int head = w >> 6;
  const int rem = w & 63;
  const int split = rem >> 5;
  const int q0 = (rem & 31) * 128 + wid * 32;

  const int kc = meta[0];
  const int nkt = (kc + 63) >> 6;
  const int th = nkt >> 1;
  const int t0 = split ? th : 0;
  const int t1 = split ? nkt : th;

  // Q B-frags: lane n = q = l31, k = dc*16 + hf*8 + j  (held in regs whole kernel)
  const f16* Qp = Qh + ((size_t)head * S_LEN + q0 + l31) * DHEAD;
  f16x8 qf[4];
  #pragma unroll
  for (int dc = 0; dc < 4; ++dc) qf[dc] = *(const f16x8*)(Qp + dc * 16 + hf * 8);

  f32x16 accO[2] = {};     // [dh]: O columns dh*32+l31, rows = C-layout
  float ls0 = 0.f, ls1 = 0.f, ls2 = 0.f, ls3 = 0.f;

  const char* kbase = (const char*)(Kc + (size_t)head * S_LEN * DHEAD);
  const char* vbase = (const char*)(Vtc + (size_t)head * DHEAD * S_LEN);

  const int c0row = tid >> 3,         c0slot = tid & 7;
  const int c1row = (256 + tid) >> 3, c1slot = tid & 7;
  const int gs0 = c0slot ^ (c0row & 7);
  const int gs1 = c1slot ^ (c1row & 7);

  auto stage = [&](int t, int buf) {
    const int j0 = t * 64;
    async_copy16(kbase + (size_t)(j0 + c0row) * 128 + gs0 * 16,
                 (char*)&lK[buf][0] + (wid * 64) * 16);
    async_copy16(vbase + (size_t)c0row * (S_LEN * 2) + (size_t)j0 * 2 + gs0 * 16,
                 (char*)&lV[buf][0] + (wid * 64) * 16);
    async_copy16(kbase + (size_t)(j0 + c1row) * 128 + gs1 * 16,
                 (char*)&lK[buf][0] + (256 + wid * 64) * 16);
    async_copy16(vbase + (size_t)c1row * (S_LEN * 2) + (size_t)j0 * 2 + gs1 * 16,
                 (char*)&lV[buf][0] + (256 + wid * 64) * 16);
  };

  int cur = 0;
  if (t0 < t1) {
    stage(t0, 0);
    __syncthreads();
  }

  for (int t = t0; t < t1; ++t) {
    const bool more = (t + 1 < t1);
    if (more) stage(t + 1, cur ^ 1);

    #pragma unroll
    for (int mh = 0; mh < 2; ++mh) {
      f16x8 af[4];
      const int arow = mh * 32 + l31;
      #pragma unroll
      for (int dc = 0; dc < 4; ++dc)
        af[dc] = *(const f16x8*)&lK[cur][arow * 64 + ((((dc << 1) | hf) ^ r7) * 8)];
      f32x16 s = {};
      #pragma unroll
      for (int dc = 0; dc < 4; ++dc)
        s = __builtin_amdgcn_mfma_f32_32x32x16_f16(af[dc], qf[dc], s, 0, 0, 0);
      #pragma unroll
      for (int u = 0; u < 16; ++u) {
        s[u] = fast_exp2(s[u]);
        if ((u & 3) == 0) ls0 += s[u];
        else if ((u & 3) == 1) ls1 += s[u];
        else if ((u & 3) == 2) ls2 += s[u];
        else ls3 += s[u];
      }
      #pragma unroll
      for (int cc = 0; cc < 2; ++cc) {
        f16x8 pf;
        #pragma unroll
        for (int u = 0; u < 8; ++u) pf[u] = (f16)s[8 * cc + u];
        const int c2 = mh * 2 + cc;
        #pragma unroll
        for (int dh = 0; dh < 2; ++dh) {
          const int vrow = dh * 32 + l31;
          f16x8 vf = *(const f16x8*)&lV[cur][vrow * 64 + ((((c2 << 1) | hf) ^ r7) * 8)];
          accO[dh] = __builtin_amdgcn_mfma_f32_32x32x16_f16(pf, vf, accO[dh], 0, 0, 0);
        }
      }
    }

    if (more) {
      __syncthreads();
      cur ^= 1;
    }
  }

  float lsum = (ls0 + ls1) + (ls2 + ls3);
  lsum += __shfl_xor(lsum, 32);
  if (split == 1) lsum -= (float)(nkt * 64 - kc);
  if (hf == 0)
    PL[((size_t)split * NHEAD + head) * S_LEN + q0 + l31] = lsum;

  // coalesced PO store: bounce wave's 32x64 f16 O-tile through LDS (reuse dead lK, 16KB),
  // then stream out as 1KB fully-contiguous wave stores (kills 2.36x write amplification
  // measured in r2: scattered 64B C-layout segments -> partial-line write-allocate).
  __syncthreads();                       // all waves done reading lK/lV
  f16* ost = (f16*)lK;
  #pragma unroll
  for (int dh = 0; dh < 2; ++dh)
    #pragma unroll
    for (int reg = 0; reg < 16; ++reg) {
      int row = (reg & 3) + 8 * (reg >> 2) + 4 * hf;
      ost[wid * 2048 + row * 64 + dh * 32 + l31] = (f16)accO[dh][reg];
    }
  f16* PO = split ? PO1 : PO0;
  const f16* osrc = ost + wid * 2048;    // wave-private 4KB; intra-wave dep only (lgkmcnt)
  #pragma unroll
  for (int p = 0; p < 4; ++p) {
    int row = p * 8 + (lane >> 3), sl = lane & 7;
    f16x8 v = *(const f16x8*)&osrc[row * 64 + sl * 8];
    *(f16x8*)&PO[((size_t)head * S_LEN + q0 + row) * DHEAD + sl * 8] = v;
  }
}

// ---------------- output projection GEMM: 128x64 tiles, BK=64, 384 blocks, XCD-grouped ---
// vs r1: grid 192 (0.75 blk/CU, fully exposed barrier drains) -> 384 blocks (1.5/CU);
// BK 32->64 halves barrier count and gives 8 MFMA/wave/step (4x compute per drain).
__global__ __launch_bounds__(256) void k_out(
    const f16* __restrict__ PO0, const f16* __restrict__ PO1,
    const float* __restrict__ PL, const f16* __restrict__ wo,
    const float* __restrict__ bo, float* __restrict__ out) {
  __shared__ __attribute__((aligned(16))) f16 lA[128 * 64];   // 16KB
  __shared__ __attribute__((aligned(16))) f16 lB[64 * 64];    // 8KB
  __shared__ float linv[NHEAD * 128];
  const int tid = threadIdx.x;
  const int wid = tid >> 6, lane = tid & 63;
  const int hf = lane >> 5, l31 = lane & 31;
  const int wm = wid >> 1, wn = wid & 1;     // 2x2 waves of 64m x 32n
  const int lid = blockIdx.x;
  const int w = ((lid & 7) * 48) + (lid >> 3);   // XCD-grouped: 48 units/XCD share m-tiles
  const int nb = (w % 12) * 64;
  const int m0 = (w / 12) * 128;

  for (int i = tid; i < NHEAD * 128; i += 256) {
    int h = i >> 7, r = i & 127;
    float l = PL[(size_t)h * S_LEN + m0 + r] + PL[(size_t)(NHEAD + h) * S_LEN + m0 + r];
    linv[i] = 1.0f / l;
  }
  __syncthreads();

  f32x16 acc[2] = {};   // [mi]

  for (int head = 0; head < NHEAD; ++head) {   // BK=64 == one head per step
    // A: combine PO splits, scale by 1/l; 128 rows x 64 d = 1024 16B chunks
    #pragma unroll
    for (int it = 0; it < 4; ++it) {
      int c = it * 256 + tid;
      int row = c >> 3, slot = c & 7;
      int gs = slot ^ (row & 7);
      size_t pi = ((size_t)head * S_LEN + m0 + row) * DHEAD + gs * 8;
      f16x8 a0 = *(const f16x8*)(PO0 + pi);
      f16x8 a1 = *(const f16x8*)(PO1 + pi);
      float il = linv[head * 128 + row];
      f16x8 av;
      #pragma unroll
      for (int u = 0; u < 8; ++u) av[u] = (f16)(((float)a0[u] + (float)a1[u]) * il);
      *(f16x8*)&lA[c * 8] = av;
    }
    // B: wo rows (output cols) nb..nb+63, k-range head*64..+64; 512 chunks async
    #pragma unroll
    for (int it = 0; it < 2; ++it) {
      int c = it * 256 + tid;
      int row = c >> 3, slot = c & 7;
      int gs = slot ^ (row & 7);
      async_copy16((const char*)(wo + (size_t)(nb + row) * HDIM + head * 64) + gs * 16,
                   (char*)lB + (it * 256 + wid * 64) * 16);
    }
    __syncthreads();
    #pragma unroll
    for (int kk = 0; kk < 4; ++kk) {
      f16x8 af[2], bf;
      #pragma unroll
      for (int mi = 0; mi < 2; ++mi) {
        int row = wm * 64 + mi * 32 + l31;
        af[mi] = *(const f16x8*)&lA[row * 64 + ((((kk << 1) | hf) ^ (row & 7)) * 8)];
      }
      int rb = wn * 32 + l31;
      bf = *(const f16x8*)&lB[rb * 64 + ((((kk << 1) | hf) ^ (rb & 7)) * 8)];
      #pragma unroll
      for (int mi = 0; mi < 2; ++mi)
        acc[mi] = __builtin_amdgcn_mfma_f32_32x32x16_f16(af[mi], bf, acc[mi], 0, 0, 0);
    }
    __syncthreads();
  }

  const int n = nb + wn * 32 + l31;
  const float b = bo[n];
  #pragma unroll
  for (int mi = 0; mi < 2; ++mi) {
    #pragma unroll
    for (int reg = 0; reg < 16; ++reg) {
      int s = m0 + wm * 64 + mi * 32 + (reg & 3) + 8 * (reg >> 2) + 4 * hf;
      out[(size_t)s * HDIM + n] = acc[mi][reg] + b;
    }
  }
}

extern "C" void kernel_launch(void* const* d_in, const int* in_sizes, int n_in,
                              void* d_out, int out_size, void* d_ws, size_t ws_size,
                              hipStream_t stream) {
  const float* x  = (const float*)d_in[0];
  const float* Wq = (const float*)d_in[1];
  const float* bq = (const float*)d_in[2];
  const float* Wk = (const float*)d_in[3];
  const float* bk = (const float*)d_in[4];
  const float* Wv = (const float*)d_in[5];
  const float* bv = (const float*)d_in[6];
  const float* Wo = (const float*)d_in[7];
  const float* bo = (const float*)d_in[8];
  const int*   mask = (const int*)d_in[9];
  float* out = (float*)d_out;

  char* ws = (char*)d_ws;
  int* meta  = (int*)(ws + OFF_META);
  int* ridx  = (int*)(ws + OFF_RIDX);
  f16* xb    = (f16*)(ws + OFF_XB);
  f16* wqkv  = (f16*)(ws + OFF_WQKV);
  f16* wob   = (f16*)(ws + OFF_WO);
  f16* Qh    = (f16*)(ws + OFF_Q);
  f16* Kc    = (f16*)(ws + OFF_K);
  f16* Vtc   = (f16*)(ws + OFF_VT);
  f16* Vrow  = (f16*)(ws + OFF_VR);
  f16* PO0   = (f16*)(ws + OFF_VR);     // reuses Vrow after k_vt
  f16* PO1   = (f16*)(ws + OFF_PO1);
  float* PL  = (float*)(ws + OFF_WQKV); // reuses wqkv after k_qkv

  k_prep<<<dim3(5377), 256, 0, stream>>>(x, Wq, Wk, Wv, Wo, mask, xb, ridx, meta);
  k_qkv<<<dim3(18, 32), 256, 0, stream>>>(xb, wqkv, bq, bk, bv, ridx, meta, Qh, Kc, Vrow);
  k_vt<<<dim3(64, NHEAD), 256, 0, stream>>>(meta, Vrow, Vtc, Kc);
  k_attn<<<dim3(768), 256, 0, stream>>>(Qh, Kc, Vtc, meta, PO0, PO1, PL);
  k_out<<<dim3(384), 256, 0, stream>>>(PO0, PO1, PL, wob, bo, out);
}